// Round 2
// baseline (256.932 us; speedup 1.0000x reference)
//
#include <hip/hip_runtime.h>

// TotalVariationLoss: mean over (B,N,K) of squared distances to the K=8
// nearest neighbors (self excluded) of each of B*N 3D points.
// Brute-force O(N^2) scan; only the SUM of each point's 8 smallest non-self
// d2 is needed (reference's gathered "variations" ARE those distances).

constexpr int B_    = 4;
constexpr int N_    = 8192;
constexpr int KNN   = 8;
constexpr int SPLIT = 4;                 // candidate-chunks per query
constexpr int BLOCK = 256;
constexpr int QPB   = BLOCK / SPLIT;     // 64 queries per block
constexpr int TILE  = 2048;              // candidates staged per LDS tile

__global__ __launch_bounds__(BLOCK, 2)
void knn_tv_kernel(const float* __restrict__ pts, float* __restrict__ out) {
    __shared__ float4 tile[TILE];        // 32 KiB -> 2 blocks/CU
    __shared__ float  blocksum;

    const int tid = threadIdx.x;
    const int s   = tid & (SPLIT - 1);   // chunk id, adjacent lanes per query
    const int ql  = tid >> 2;            // local query
    const int bpb = N_ / QPB;            // 128 blocks per batch
    const int b   = blockIdx.x / bpb;
    const int n   = (blockIdx.x % bpb) * QPB + ql;

    const float* __restrict__ base = pts + (size_t)b * (N_ * 3);
    const float qx = base[n * 3 + 0];
    const float qy = base[n * 3 + 1];
    const float qz = base[n * 3 + 2];
    const float qsq = fmaf(qx, qx, fmaf(qy, qy, qz * qz));
    const float m2x = -2.0f * qx, m2y = -2.0f * qy, m2z = -2.0f * qz;

    if (tid == 0) blocksum = 0.0f;

    float h[KNN];                        // ascending top-8 (h[7] = worst)
#pragma unroll
    for (int k = 0; k < KNN; ++k) h[k] = 1e30f;

    for (int t = 0; t < N_; t += TILE) {
        __syncthreads();                 // also covers blocksum init (1st iter)
        for (int j = tid; j < TILE; j += BLOCK) {
            const float* src = base + (size_t)(t + j) * 3;
            const float x = src[0], y = src[1], z = src[2];
            tile[j] = make_float4(x, y, z, fmaf(x, x, fmaf(y, y, z * z)));
        }
        __syncthreads();

        // this thread sees candidate m = t + SPLIT*i + s; self at i==iself
        const int jself = n - t;
        const int iself = (jself >= 0 && jself < TILE && (jself & (SPLIT - 1)) == s)
                              ? (jself >> 2) : -1;

#pragma unroll 4
        for (int i = 0; i < TILE / SPLIT; ++i) {
            const float4 c = tile[i * SPLIT + s];   // 16-way broadcast, conflict-free
            // expanded form: d2 = qsq + csq - 2*dot  (csq staged in c.w)
            float d2 = fmaf(m2x, c.x, fmaf(m2y, c.y, fmaf(m2z, c.z, qsq + c.w)));
            d2 = (i == iself) ? 1e30f : d2;         // exclude self exactly
            if (__any(d2 < h[KNN - 1])) {
                // branch-free sorted insert: bubble d through the ascending list
                float d = d2;
#pragma unroll
                for (int k = 0; k < KNN; ++k) {
                    const float lo = fminf(h[k], d);
                    d    = fmaxf(h[k], d);
                    h[k] = lo;
                }
            }
        }
    }

    // Merge the 4 per-chunk top-8 lists (lanes ql*4+s, s=0..3).
    // Stage 1 (xor 1): bitonic top-k merge C_k = min(A_k, B_{7-k}) gives the
    // 8 smallest of the union as a bitonic sequence; 3-stage cleanup sorts it.
    {
        float bb[KNN], c[KNN];
#pragma unroll
        for (int k = 0; k < KNN; ++k) bb[k] = __shfl_xor(h[k], 1, 64);
#pragma unroll
        for (int k = 0; k < KNN; ++k) c[k] = fminf(h[k], bb[KNN - 1 - k]);
#pragma unroll
        for (int stride = KNN / 2; stride >= 1; stride >>= 1) {
#pragma unroll
            for (int k = 0; k < KNN; ++k) {
                if ((k & stride) == 0) {
                    const float lo = fminf(c[k], c[k + stride]);
                    c[k + stride]  = fmaxf(c[k], c[k + stride]);
                    c[k] = lo;
                }
            }
        }
#pragma unroll
        for (int k = 0; k < KNN; ++k) h[k] = c[k];
    }
    // Stage 2 (xor 2): only the SUM of the merged top-8 is needed; the
    // elementwise mins already form the top-8 multiset — skip the cleanup.
    float qsum = 0.0f;
    {
        float bb[KNN];
#pragma unroll
        for (int k = 0; k < KNN; ++k) bb[k] = __shfl_xor(h[k], 2, 64);
#pragma unroll
        for (int k = 0; k < KNN; ++k) qsum += fminf(h[k], bb[KNN - 1 - k]);
    }

    // All 4 lanes of a query group hold the same qsum -> wave sum counts each
    // query 4x; reduce, scale by 1/4, one LDS atomic per wave.
#pragma unroll
    for (int off = 32; off >= 1; off >>= 1) qsum += __shfl_xor(qsum, off, 64);
    if ((tid & 63) == 0) atomicAdd(&blocksum, qsum * 0.25f);
    __syncthreads();
    if (tid == 0) {
        atomicAdd(out, blocksum * (1.0f / ((float)B_ * N_ * KNN)));
    }
}

extern "C" void kernel_launch(void* const* d_in, const int* in_sizes, int n_in,
                              void* d_out, int out_size, void* d_ws, size_t ws_size,
                              hipStream_t stream) {
    const float* pts = (const float*)d_in[0];
    float* out = (float*)d_out;
    hipMemsetAsync(out, 0, (size_t)out_size * sizeof(float), stream);  // 0xAA-poisoned
    dim3 grid(B_ * (N_ / QPB));                     // 512 blocks, 2/CU resident
    knn_tv_kernel<<<grid, BLOCK, 0, stream>>>(pts, out);
}